// Round 8
// baseline (99.531 us; speedup 1.0000x reference)
//
#include <hip/hip_runtime.h>
#include <stdint.h>

#define BATCH   32768
#define NBITS   512
#define NWORDS  512               // BATCH / 64
#define NSLICE  32                // K-split
#define SW      16                // words per slice = NWORDS / NSLICE
#define NTILE   36                // 8x8 lower-triangle of 64x64 tiles
#define NTASK   (NTILE * NSLICE)  // 1152 gram tasks
#define NBLK    256
#define NTHR    512

typedef unsigned long long u64;

struct Ctrl { int cnt; int gen; int done; int pad; };

// Device-scope reusable spin barrier. Safe: all NBLK blocks are co-resident
// (1 block/CU nominal; worst-case packing capacity 4/CU >> 1). cnt self-resets
// each use; gen is monotone across graph replays; ctrl zeroed by memset node.
__device__ inline void gbar(int* cnt, int* gen) {
    __syncthreads();
    if (threadIdx.x == 0) {
        __threadfence();
        const int g = atomicAdd(gen, 0);
        const int old = atomicAdd(cnt, 1);
        if (old == NBLK - 1) {
            atomicExch(cnt, 0);
            __threadfence();
            atomicAdd(gen, 1);
        } else {
            while (atomicAdd(gen, 0) == g) __builtin_amdgcn_s_sleep(8);
        }
        __threadfence();
    }
    __syncthreads();
}

__global__ __launch_bounds__(NTHR, 2) void fused_kernel(
    const float* __restrict__ bits,
    u64* __restrict__ packed,
    unsigned short* __restrict__ Cp,     // NSLICE x 512 x 512 u16 (16 MB)
    double* __restrict__ lg,
    int* __restrict__ c1,
    Ctrl* __restrict__ ctrl,
    double* __restrict__ bsum,
    int* __restrict__ bcnt,
    float* __restrict__ out)
{
    __shared__ u64 lds[2][2][SW][64];    // [group][side][word][col] = 32 KB
    __shared__ double ssum[NTHR];
    __shared__ int scnt[NTHR];
    __shared__ int lastFlag;

    const int tid = threadIdx.x;
    const int b   = blockIdx.x;
    const int gid = b * NTHR + tid;

    // ================= Phase A: pack + lg table + zero c1 =================
    if (gid <= BATCH) lg[gid] = (gid > 0) ? log((double)gid) : 0.0;
    if (gid < NBITS)  c1[gid] = 0;

    {
        const int wid  = tid >> 6;
        const int lane = tid & 63;
        const int gw   = b * 8 + wid;     // 0..2047, exactly one task per wave
        const int w    = gw >> 2;         // word 0..511
        const int q    = gw & 3;          // column quarter
        const int c0   = q * 128 + lane * 2;

        u64 m0 = 0, m1 = 0;
        const float* base = bits + (size_t)w * 64 * NBITS + c0;
#pragma unroll 16
        for (int r = 0; r < 64; ++r) {
            float2 v = *reinterpret_cast<const float2*>(base + (size_t)r * NBITS);
            const u64 bb = 1ull << r;
            if (v.x > 0.0f) m0 |= bb;
            if (v.y > 0.0f) m1 |= bb;
        }
        ulonglong2 st; st.x = m0; st.y = m1;
        *reinterpret_cast<ulonglong2*>(&packed[(size_t)w * NBITS + c0]) = st;
    }

    gbar(&ctrl->cnt, &ctrl->gen);

    // ================= Phase B: partial Gram (R5 shape, u16 out) ==========
    // 1152 tasks = (tile of 36 [64x64], slice of 32 [16 words]). Group =
    // 256 threads (2/block, 512 groups); group g does tasks g, g+512, g+1024.
    // 4x4 register tile, interleaved cols {x,x+1,x+32,x+33}: conflict-free-ish
    // b128 LDS reads, 4 B LDS per popcll-term.
    {
        const int grp = tid >> 8;         // 0,1
        const int gt  = tid & 255;
        const int gg  = b * 2 + grp;      // group id 0..511

        for (int it = 0; it < 3; ++it) {
            const int task = gg + it * 512;
            int i0 = 0, j0 = 0, w0 = 0;
            bool diag = false;
            const bool active = (task < NTASK);
            if (active) {
                const int s = task & (NSLICE - 1);
                const int t = task >> 5;
                int bi = (int)((sqrtf(8.0f * (float)t + 1.0f) - 1.0f) * 0.5f);
                while ((bi + 1) * (bi + 2) / 2 <= t) ++bi;
                while (bi * (bi + 1) / 2 > t) --bi;
                const int bj = t - bi * (bi + 1) / 2;
                i0 = bi * 64; j0 = bj * 64; w0 = (task & (NSLICE - 1)) * SW;
                diag = (bi == bj);
                (void)s;

                // stage 16 words x 64 cols per side (16 KB)
                for (int q2 = gt; q2 < SW * 32; q2 += 256) {   // 2 iterations
                    const int wo = q2 >> 5, cp = (q2 & 31) * 2;
                    const size_t g = (size_t)(w0 + wo) * NBITS;
                    *reinterpret_cast<ulonglong2*>(&lds[grp][0][wo][cp]) =
                        *reinterpret_cast<const ulonglong2*>(&packed[g + i0 + cp]);
                    if (!diag)
                        *reinterpret_cast<ulonglong2*>(&lds[grp][1][wo][cp]) =
                            *reinterpret_cast<const ulonglong2*>(&packed[g + j0 + cp]);
                }
            }
            __syncthreads();
            if (active) {
                const int tj2 = (gt & 15) * 2;
                const int ti2 = (gt >> 4) * 2;
                const u64 (*LI)[64] = lds[grp][0];
                const u64 (*LJ)[64] = diag ? lds[grp][0] : lds[grp][1];

                int acc[4][4] = {};
#pragma unroll
                for (int w = 0; w < SW; ++w) {
                    const u64 a0 = LI[w][ti2],      a1 = LI[w][ti2 + 1];
                    const u64 a2 = LI[w][ti2 + 32], a3 = LI[w][ti2 + 33];
                    const u64 b0 = LJ[w][tj2],      b1 = LJ[w][tj2 + 1];
                    const u64 b2 = LJ[w][tj2 + 32], b3 = LJ[w][tj2 + 33];
                    acc[0][0] += __popcll(a0 & b0); acc[0][1] += __popcll(a0 & b1);
                    acc[0][2] += __popcll(a0 & b2); acc[0][3] += __popcll(a0 & b3);
                    acc[1][0] += __popcll(a1 & b0); acc[1][1] += __popcll(a1 & b1);
                    acc[1][2] += __popcll(a1 & b2); acc[1][3] += __popcll(a1 & b3);
                    acc[2][0] += __popcll(a2 & b0); acc[2][1] += __popcll(a2 & b1);
                    acc[2][2] += __popcll(a2 & b2); acc[2][3] += __popcll(a2 & b3);
                    acc[3][0] += __popcll(a3 & b0); acc[3][1] += __popcll(a3 & b1);
                    acc[3][2] += __popcll(a3 & b2); acc[3][3] += __popcll(a3 & b3);
                }

                unsigned short* cs = Cp + ((size_t)(task & (NSLICE - 1)) << 18);
                const int io[4] = {ti2, ti2 + 1, ti2 + 32, ti2 + 33};
#pragma unroll
                for (int a = 0; a < 4; ++a) {
                    const size_t row = (size_t)(i0 + io[a]) * NBITS + j0;
                    ushort2 u;
                    u.x = (unsigned short)acc[a][0]; u.y = (unsigned short)acc[a][1];
                    *reinterpret_cast<ushort2*>(&cs[row + tj2]) = u;
                    u.x = (unsigned short)acc[a][2]; u.y = (unsigned short)acc[a][3];
                    *reinterpret_cast<ushort2*>(&cs[row + tj2 + 32]) = u;
                }
                if (diag && ti2 == tj2) {
#pragma unroll
                    for (int a = 0; a < 4; ++a)
                        atomicAdd(&c1[i0 + io[a]], acc[a][a]);
                }
            }
            __syncthreads();
        }
    }

    gbar(&ctrl->cnt, &ctrl->gen);

    // ================= Phase C: MI epilogue + reduction ===================
    // Balanced rows: threads 0-255 -> row b (j = tid), threads 256-511 ->
    // row 511-b (j = tid-256 and tid). Exact integer counts + f64 log table.
    const double invB = 1.0 / (double)BATCH;
    const double lgB  = lg[BATCH];
    double lsum = 0.0;
    int lcnt = 0;

    {
        int i, jlist[2]; int nj = 0;
        if (tid < 256) {
            i = b;
            if (tid < i) jlist[nj++] = tid;
        } else {
            i = 511 - b;
            const int jj = tid - 256;
            if (jj < i)       jlist[nj++] = jj;
            if (jj + 256 < i) jlist[nj++] = jj + 256;
        }
        const int ci = c1[i];
        for (int k = 0; k < nj; ++k) {
            const int j = jlist[k];
            int n11 = 0;
#pragma unroll
            for (int s = 0; s < NSLICE; ++s)
                n11 += Cp[((size_t)s << 18) + (size_t)i * NBITS + j];
            const int cj = c1[j];

            const int pim[2] = {BATCH - ci, ci};
            const int pjn[2] = {BATCH - cj, cj};
            const int nmn[2][2] = {{BATCH - ci - cj + n11, cj - n11},
                                   {ci - n11, n11}};
#pragma unroll
            for (int m = 0; m < 2; ++m)
#pragma unroll
                for (int n = 0; n < 2; ++n) {
                    const int c_mn = nmn[m][n];
                    if (c_mn > 0 && pim[m] > 0 && pjn[n] > 0) {
                        lsum += (double)c_mn * invB *
                                (lg[c_mn] + lgB - lg[pim[m]] - lg[pjn[n]]);
                        ++lcnt;
                    }
                }
        }
    }

    ssum[tid] = lsum;
    scnt[tid] = lcnt;
    __syncthreads();
    for (int off = 256; off > 0; off >>= 1) {
        if (tid < off) {
            ssum[tid] += ssum[tid + off];
            scnt[tid] += scnt[tid + off];
        }
        __syncthreads();
    }
    if (tid == 0) {
        bsum[b] = ssum[0];
        bcnt[b] = scnt[0];
        __threadfence();
        lastFlag = (atomicAdd(&ctrl->done, 1) == NBLK - 1);
    }
    __syncthreads();
    if (!lastFlag) return;

    __threadfence();
    if (tid < 256) { ssum[tid] = bsum[tid]; scnt[tid] = bcnt[tid]; }
    __syncthreads();
    for (int off = 128; off > 0; off >>= 1) {
        if (tid < off) {
            ssum[tid] += ssum[tid + off];
            scnt[tid] += scnt[tid + off];
        }
        __syncthreads();
    }
    if (tid == 0) out[0] = (float)(ssum[0] / (double)scnt[0]);
}

// ---------------------------------------------------------------------------
extern "C" void kernel_launch(void* const* d_in, const int* in_sizes, int n_in,
                              void* d_out, int out_size, void* d_ws, size_t ws_size,
                              hipStream_t stream) {
    const float* bits = (const float*)d_in[0];
    char* ws = (char*)d_ws;
    u64*            packed = (u64*)ws;                                 // 2 MB
    unsigned short* Cp     = (unsigned short*)(ws + (2u << 20));       // 16 MB
    double*         lg     = (double*)(ws + (18u << 20));              // 256 KB + 8 B
    int*            c1     = (int*)(ws + (18u << 20) + (512u << 10));  // 2 KB
    Ctrl*           ctrl   = (Ctrl*)(ws + (18u << 20) + (516u << 10)); // 16 B
    double*         bsum   = (double*)(ws + (18u << 20) + (520u << 10)); // 2 KB
    int*            bcnt   = (int*)(ws + (18u << 20) + (524u << 10));  // 1 KB

    hipMemsetAsync(ctrl, 0, sizeof(Ctrl), stream);
    fused_kernel<<<NBLK, NTHR, 0, stream>>>(bits, packed, Cp, lg, c1, ctrl,
                                            bsum, bcnt, (float*)d_out);
}

// Round 9
// 52.909 us; speedup vs baseline: 1.8812x; 1.8812x over previous
//
#include <hip/hip_runtime.h>
#include <stdint.h>

#define BATCH   32768
#define NBITS   512
#define NWORDS  512          // BATCH / 64
#define NSLICE  32           // K-split: 36 tiles * 32 = 1152 blocks (~4.5/CU)
#define SW      16           // words per slice = NWORDS / NSLICE
#define NTILE   36           // 8x8 lower-triangle of 64x64 tiles
#define MIGRID  512

typedef unsigned long long u64;

// ---------------------------------------------------------------------------
// Pass 1: bit-pack + f64 log table + zero c1/done.  (exact R5 shape)
// 2048 wave-tasks (2/SIMD): wave = (word w, column-quarter q); lane reads
// float2, builds two u64 row-masks, ulonglong2 store. BW-bound: 64 MB.
// ---------------------------------------------------------------------------
__global__ __launch_bounds__(256) void pack_kernel(const float* __restrict__ bits,
                                                   u64* __restrict__ packed,
                                                   double* __restrict__ lg,
                                                   int* __restrict__ c1,
                                                   int* __restrict__ done) {
    const int gid = blockIdx.x * 256 + threadIdx.x;   // 0..131071

    if (gid <= BATCH) lg[gid] = (gid > 0) ? log((double)gid) : 0.0;
    if (gid < NBITS) c1[gid] = 0;
    if (gid == NBITS) *done = 0;

    const int wv   = threadIdx.x >> 6;
    const int lane = threadIdx.x & 63;
    const int gw   = blockIdx.x * 4 + wv;     // 0..2047
    const int w    = gw >> 2;                 // word 0..511
    const int q    = gw & 3;                  // column quarter
    const int c0   = q * 128 + lane * 2;

    u64 m0 = 0, m1 = 0;
    const float* base = bits + (size_t)w * 64 * NBITS + c0;
#pragma unroll 16
    for (int r = 0; r < 64; ++r) {
        float2 v = *reinterpret_cast<const float2*>(base + (size_t)r * NBITS);
        const u64 b = 1ull << r;
        if (v.x > 0.0f) m0 |= b;
        if (v.y > 0.0f) m1 |= b;
    }
    ulonglong2 st; st.x = m0; st.y = m1;
    *reinterpret_cast<ulonglong2*>(&packed[(size_t)w * NBITS + c0]) = st;
}

// ---------------------------------------------------------------------------
// Pass 2: partial Gram — EXACT R5 shape (the best-measured config), with the
// single delta that stores are u16 (per-slice counts <= 1024). Block =
// (tile t of 36 [64x64], slice s of 32 [16 words]), 256 threads, 4x4
// register tile with interleaved cols {x,x+1,x+32,x+33} (conflict-free b128
// LDS reads, 4 B LDS per popcll-term). 1152 blocks, 16 KB LDS. Diagonal
// tiles accumulate c1 via int atomics (exact, order-independent).
// ---------------------------------------------------------------------------
__global__ __launch_bounds__(256) void gram_kernel(const u64* __restrict__ packed,
                                                   unsigned short* __restrict__ Cp,
                                                   int* __restrict__ c1) {
    __shared__ u64 ldsI[SW][64];
    __shared__ u64 ldsJ[SW][64];

    const int s = blockIdx.x & (NSLICE - 1);  // K-slice 0..31
    const int t = blockIdx.x >> 5;            // tile 0..35
    int bi = (int)((sqrtf(8.0f * (float)t + 1.0f) - 1.0f) * 0.5f);
    while ((bi + 1) * (bi + 2) / 2 <= t) ++bi;
    while (bi * (bi + 1) / 2 > t) --bi;
    const int bj = t - bi * (bi + 1) / 2;

    const int i0 = bi * 64, j0 = bj * 64;
    const int w0 = s * SW;
    const bool diag = (bi == bj);

    // stage SW words x 64 cols per side (8 KB each side)
    for (int q = threadIdx.x; q < SW * 32; q += 256) {
        const int wo = q >> 5, cp = (q & 31) * 2;
        const size_t g = (size_t)(w0 + wo) * NBITS;
        *reinterpret_cast<ulonglong2*>(&ldsI[wo][cp]) =
            *reinterpret_cast<const ulonglong2*>(&packed[g + i0 + cp]);
        if (!diag)
            *reinterpret_cast<ulonglong2*>(&ldsJ[wo][cp]) =
                *reinterpret_cast<const ulonglong2*>(&packed[g + j0 + cp]);
    }
    __syncthreads();

    const int tj2 = (threadIdx.x & 15) * 2;   // j-col base (fast dim, even)
    const int ti2 = (threadIdx.x >> 4) * 2;   // i-col base (even)
    const u64 (*BJ)[64] = diag ? ldsI : ldsJ;

    int acc[4][4] = {};
#pragma unroll
    for (int w = 0; w < SW; ++w) {
        const u64 a0 = ldsI[w][ti2],      a1 = ldsI[w][ti2 + 1];
        const u64 a2 = ldsI[w][ti2 + 32], a3 = ldsI[w][ti2 + 33];
        const u64 b0 = BJ[w][tj2],        b1 = BJ[w][tj2 + 1];
        const u64 b2 = BJ[w][tj2 + 32],   b3 = BJ[w][tj2 + 33];
        acc[0][0] += __popcll(a0 & b0); acc[0][1] += __popcll(a0 & b1);
        acc[0][2] += __popcll(a0 & b2); acc[0][3] += __popcll(a0 & b3);
        acc[1][0] += __popcll(a1 & b0); acc[1][1] += __popcll(a1 & b1);
        acc[1][2] += __popcll(a1 & b2); acc[1][3] += __popcll(a1 & b3);
        acc[2][0] += __popcll(a2 & b0); acc[2][1] += __popcll(a2 & b1);
        acc[2][2] += __popcll(a2 & b2); acc[2][3] += __popcll(a2 & b3);
        acc[3][0] += __popcll(a3 & b0); acc[3][1] += __popcll(a3 & b1);
        acc[3][2] += __popcll(a3 & b2); acc[3][3] += __popcll(a3 & b3);
    }

    unsigned short* out = Cp + ((size_t)s << 18);
    const int io[4] = {ti2, ti2 + 1, ti2 + 32, ti2 + 33};
#pragma unroll
    for (int a = 0; a < 4; ++a) {
        const size_t row = (size_t)(i0 + io[a]) * NBITS + j0;
        ushort2 u;
        u.x = (unsigned short)acc[a][0]; u.y = (unsigned short)acc[a][1];
        *reinterpret_cast<ushort2*>(&out[row + tj2]) = u;
        u.x = (unsigned short)acc[a][2]; u.y = (unsigned short)acc[a][3];
        *reinterpret_cast<ushort2*>(&out[row + tj2 + 32]) = u;
    }

    if (diag && ti2 == tj2) {
#pragma unroll
        for (int a = 0; a < 4; ++a)
            atomicAdd(&c1[i0 + io[a]], acc[a][a]);
    }
}

// ---------------------------------------------------------------------------
// Pass 3 (+fused final): per-pair MI terms. Block i, thread j (+256). n11 =
// coalesced sum of 32 u16 slice partials of row i; marginals from c1.
// Log-table epilogue, deterministic block reduction -> bsum/bcnt; last block
// (done counter + threadfence) reduces the 512 partials and writes out.
// ---------------------------------------------------------------------------
__global__ __launch_bounds__(256) void mi_kernel(const unsigned short* __restrict__ Cp,
                                                 const int* __restrict__ c1,
                                                 const double* __restrict__ lg,
                                                 double* __restrict__ bsum,
                                                 int* __restrict__ bcnt,
                                                 int* __restrict__ done,
                                                 float* __restrict__ out) {
    const double invB = 1.0 / (double)BATCH;
    const int i = blockIdx.x;
    const int ci = c1[i];
    const double lgB = lg[BATCH];
    double lsum = 0.0;
    int lcnt = 0;

#pragma unroll
    for (int half = 0; half < 2; ++half) {
        const int j = half * 256 + threadIdx.x;
        if (j < i) {
            int n11 = 0;
#pragma unroll
            for (int s = 0; s < NSLICE; ++s)
                n11 += Cp[((size_t)s << 18) + (size_t)i * NBITS + j];
            const int cj = c1[j];

            const int pim[2] = {BATCH - ci, ci};
            const int pjn[2] = {BATCH - cj, cj};
            const int nmn[2][2] = {{BATCH - ci - cj + n11, cj - n11},
                                   {ci - n11, n11}};
#pragma unroll
            for (int m = 0; m < 2; ++m)
#pragma unroll
                for (int n = 0; n < 2; ++n) {
                    const int c_mn = nmn[m][n];
                    if (c_mn > 0 && pim[m] > 0 && pjn[n] > 0) {
                        lsum += (double)c_mn * invB *
                                (lg[c_mn] + lgB - lg[pim[m]] - lg[pjn[n]]);
                        ++lcnt;
                    }
                }
        }
    }

    __shared__ double ssum[256];
    __shared__ int scnt[256];
    __shared__ int lastFlag;
    ssum[threadIdx.x] = lsum;
    scnt[threadIdx.x] = lcnt;
    __syncthreads();
    for (int off = 128; off > 0; off >>= 1) {
        if (threadIdx.x < off) {
            ssum[threadIdx.x] += ssum[threadIdx.x + off];
            scnt[threadIdx.x] += scnt[threadIdx.x + off];
        }
        __syncthreads();
    }
    if (threadIdx.x == 0) {
        bsum[i] = ssum[0];
        bcnt[i] = scnt[0];
        __threadfence();
        lastFlag = (atomicAdd(done, 1) == MIGRID - 1);
    }
    __syncthreads();
    if (!lastFlag) return;

    __threadfence();
    double s2 = bsum[threadIdx.x] + bsum[threadIdx.x + 256];
    int c2 = bcnt[threadIdx.x] + bcnt[threadIdx.x + 256];
    __syncthreads();
    ssum[threadIdx.x] = s2;
    scnt[threadIdx.x] = c2;
    __syncthreads();
    for (int off = 128; off > 0; off >>= 1) {
        if (threadIdx.x < off) {
            ssum[threadIdx.x] += ssum[threadIdx.x + off];
            scnt[threadIdx.x] += scnt[threadIdx.x + off];
        }
        __syncthreads();
    }
    if (threadIdx.x == 0) out[0] = (float)(ssum[0] / (double)scnt[0]);
}

// ---------------------------------------------------------------------------
extern "C" void kernel_launch(void* const* d_in, const int* in_sizes, int n_in,
                              void* d_out, int out_size, void* d_ws, size_t ws_size,
                              hipStream_t stream) {
    const float* bits = (const float*)d_in[0];
    char* ws = (char*)d_ws;
    u64*            packed = (u64*)ws;                                   // 2 MB
    unsigned short* Cp     = (unsigned short*)(ws + (2u << 20));         // 16 MB
    double*         lg     = (double*)(ws + (18u << 20));                // 256 KB + 8 B
    int*            c1     = (int*)(ws + (18u << 20) + (512u << 10));    // 2 KB
    int*            done   = (int*)(ws + (18u << 20) + (516u << 10));    // 4 B
    double*         bsum   = (double*)(ws + (18u << 20) + (576u << 10)); // 4 KB
    int*            bcnt   = (int*)(ws + (18u << 20) + (640u << 10));    // 2 KB

    pack_kernel<<<512, 256, 0, stream>>>(bits, packed, lg, c1, done);
    gram_kernel<<<NTILE * NSLICE, 256, 0, stream>>>(packed, Cp, c1);
    mi_kernel<<<MIGRID, 256, 0, stream>>>(Cp, c1, lg, bsum, bcnt, done, (float*)d_out);
}